// Round 1
// baseline (484.793 us; speedup 1.0000x reference)
//
#include <hip/hip_runtime.h>
#include <stdint.h>

typedef unsigned short u16;
typedef __attribute__((ext_vector_type(8))) short short8;
typedef __attribute__((ext_vector_type(4))) float f32x4;
typedef __attribute__((ext_vector_type(4))) unsigned short ushort4_t;
typedef __attribute__((ext_vector_type(4))) float float4_t;

#define DEV_INLINE __device__ __forceinline__

DEV_INLINE u16 f2bf(float f) {
    union { float f; unsigned u; } x; x.f = f;
    unsigned u = x.u;
    unsigned r = (u + 0x7FFFu + ((u >> 16) & 1u)) >> 16;
    return (u16)r;
}

// ---------------- convert kernels ----------------
__global__ void conv_f32_bf16(const float* __restrict__ in, u16* __restrict__ out, long n4) {
    long i = (long)blockIdx.x * blockDim.x + threadIdx.x;
    if (i >= n4) return;
    float4_t v = ((const float4_t*)in)[i];
    ushort4_t o;
    o.x = f2bf(v.x); o.y = f2bf(v.y); o.z = f2bf(v.z); o.w = f2bf(v.w);
    ((ushort4_t*)out)[i] = o;
}

// pads rows >= rows_valid with zeros (for N-tile divisibility)
__global__ void conv_pad(const float* __restrict__ in, u16* __restrict__ out,
                         int rows_valid, long n4, int cols4) {
    long i = (long)blockIdx.x * blockDim.x + threadIdx.x;
    if (i >= n4) return;
    long row = i / cols4;
    ushort4_t o; o.x = 0; o.y = 0; o.z = 0; o.w = 0;
    if (row < rows_valid) {
        float4_t v = ((const float4_t*)in)[i];
        o.x = f2bf(v.x); o.y = f2bf(v.y); o.z = f2bf(v.z); o.w = f2bf(v.w);
    }
    ((ushort4_t*)out)[i] = o;
}

// ---------------- GEMM: C[M,N] = A[M,K] * B[N,K]^T (bt-form), bf16 in, f32 out ----------------
#define BM 128
#define BN 128
#define BK 32

DEV_INLINE void gload16(const u16* g, u16* l) {
    __builtin_amdgcn_global_load_lds((const __attribute__((address_space(1))) unsigned int*)g,
                                     (__attribute__((address_space(3))) unsigned int*)l,
                                     16, 0, 0);
}

__global__ __launch_bounds__(256) void gemm_bt(const u16* __restrict__ A, const u16* __restrict__ B,
                                               float* __restrict__ C, int M, int N, int K) {
    __shared__ u16 As[BM * BK];
    __shared__ u16 Bs[BN * BK];
    const int tid = threadIdx.x;
    const int wid = tid >> 6, lane = tid & 63;
    const int lm = lane & 15, lk = lane >> 4;
    const int wr = wid >> 1, wc = wid & 1;
    const long bm = (long)blockIdx.y * BM, bn = (long)blockIdx.x * BN;

    f32x4 acc[4][4] = {};

    const int rowS = lane >> 2;          // 0..15 (row within a 16-row chunk)
    const int colS = (lane & 3) * 8;     // 0,8,16,24 (bf16 elements)
    const u16* Ag = A + (bm + wid * 32 + rowS) * (long)K + colS;
    const u16* Bg = B + (bn + wid * 32 + rowS) * (long)K + colS;
    u16* AsW = &As[(wid * 32) * BK];
    u16* BsW = &Bs[(wid * 32) * BK];

    for (int k0 = 0; k0 < K; k0 += BK) {
        __syncthreads();                       // prev compute done before overwrite
        gload16(Ag + k0, AsW);
        gload16(Ag + 16 * (long)K + k0, AsW + 16 * BK);
        gload16(Bg + k0, BsW);
        gload16(Bg + 16 * (long)K + k0, BsW + 16 * BK);
        __syncthreads();                       // drains vmcnt -> staging complete

        short8 af[4], bfr[4];
#pragma unroll
        for (int m = 0; m < 4; ++m)
            af[m] = *(const short8*)&As[(wr * 64 + m * 16 + lm) * BK + lk * 8];
#pragma unroll
        for (int n = 0; n < 4; ++n)
            bfr[n] = *(const short8*)&Bs[(wc * 64 + n * 16 + lm) * BK + lk * 8];
#pragma unroll
        for (int m = 0; m < 4; ++m)
#pragma unroll
            for (int n = 0; n < 4; ++n)
                acc[m][n] = __builtin_amdgcn_mfma_f32_16x16x32_bf16(af[m], bfr[n], acc[m][n], 0, 0, 0);
    }

#pragma unroll
    for (int m = 0; m < 4; ++m)
#pragma unroll
        for (int n = 0; n < 4; ++n)
#pragma unroll
            for (int r = 0; r < 4; ++r)
                C[(bm + wr * 64 + m * 16 + lk * 4 + r) * (long)N + bn + wc * 64 + n * 16 + lm] = acc[m][n][r];
}

// ---------------- RMSNorm (f32 in, bf16 out) ----------------
__global__ __launch_bounds__(256) void rmsnorm_bf16(const float* __restrict__ in, const float* __restrict__ w,
                                                    u16* __restrict__ out, int ldin, int ldout, int ncols) {
    const int row = blockIdx.x, tid = threadIdx.x;
    const float* x = in + (long)row * ldin;
    float ss = 0.f;
    for (int c = tid; c < ncols; c += 256) { float v = x[c]; ss = fmaf(v, v, ss); }
#pragma unroll
    for (int off = 32; off > 0; off >>= 1) ss += __shfl_down(ss, off);
    __shared__ float part[4];
    if ((tid & 63) == 0) part[tid >> 6] = ss;
    __syncthreads();
    float tot = part[0] + part[1] + part[2] + part[3];
    float rs = rsqrtf(tot / (float)ncols + 1e-6f);
    for (int c = tid; c < ncols; c += 256) out[(long)row * ldout + c] = f2bf(x[c] * rs * w[c]);
}

// ---------------- k_pe RoPE -> K[:, :, 128:192] for all heads ----------------
__global__ void rope_k(const float* __restrict__ ckv, const int* __restrict__ pos,
                       const float* __restrict__ cosT, const float* __restrict__ sinT,
                       u16* __restrict__ Kb) {
    int idx = blockIdx.x * 256 + threadIdx.x;
    if (idx >= 2048 * 32) return;
    int s = idx >> 5, j = idx & 31;
    long p = pos[s];
    const float* row = ckv + (long)s * 640 + 512;
    float x0 = row[2 * j], x1 = row[2 * j + 1];
    float c0 = cosT[p * 64 + j],      s0 = sinT[p * 64 + j];
    float c1 = cosT[p * 64 + 32 + j], s1 = sinT[p * 64 + 32 + j];
    u16 o0 = f2bf(x0 * c0 - x1 * s0);
    u16 o1 = f2bf(x1 * c1 + x0 * s1);
#pragma unroll
    for (int h = 0; h < 16; ++h) {
        u16* kr = Kb + ((long)h * 2048 + s) * 192 + 128;
        kr[j] = o0; kr[32 + j] = o1;
    }
}

// ---------------- assemble Q (with RoPE on last 64 dims) ----------------
__global__ void build_q(const float* __restrict__ q, const int* __restrict__ pos,
                        const float* __restrict__ cosT, const float* __restrict__ sinT,
                        u16* __restrict__ Qb) {
    long idx = (long)blockIdx.x * 256 + threadIdx.x;
    if (idx >= 16L * 2048 * 192) return;
    int d = (int)(idx % 192);
    int s = (int)((idx / 192) % 2048);
    int h = (int)(idx / (192L * 2048));
    const float* qrow = q + (long)s * 3072 + h * 192;
    float val;
    if (d < 128) {
        val = qrow[d];
    } else {
        long p = pos[s];
        int dd = d - 128;
        float cv = cosT[p * 64 + dd], sv = sinT[p * 64 + dd];
        if (dd < 32) val = qrow[128 + 2 * dd] * cv - qrow[128 + 2 * dd + 1] * sv;
        else { int jj = dd - 32; val = qrow[128 + 2 * jj + 1] * cv + qrow[128 + 2 * jj] * sv; }
    }
    Qb[((long)h * 2048 + s) * 192 + d] = f2bf(val);
}

// ---------------- assemble K (nope part) and V ----------------
__global__ void build_kv(const float* __restrict__ kv, u16* __restrict__ Kb, u16* __restrict__ Vb) {
    long idx = (long)blockIdx.x * 256 + threadIdx.x;
    if (idx >= 16L * 2048 * 256) return;
    int d = (int)(idx & 255);
    int s = (int)((idx >> 8) & 2047);
    int h = (int)(idx >> 19);
    float v = kv[(long)s * 4096 + h * 256 + d];
    if (d < 128) Kb[((long)h * 2048 + s) * 192 + d] = f2bf(v);
    else         Vb[((long)h * 2048 + s) * 128 + (d - 128)] = f2bf(v);
}

// ---------------- causal flash attention ----------------
// Q,K: [H][S][192] bf16, V: [H][S][128] bf16, out: [S][H*128] bf16
__global__ __launch_bounds__(256) void attn_fwd(const u16* __restrict__ Qb, const u16* __restrict__ Kb,
                                                const u16* __restrict__ Vb, u16* __restrict__ Ao) {
    __shared__ u16 Ks[64][200];   // +8 pad: breaks 16-way bank conflict
    __shared__ u16 Vs[128][72];   // V transposed [dv][kvrow], +8 pad
    __shared__ u16 Ps[4][16][72]; // per-wave P tile

    const int h = blockIdx.y;
    const int q0 = blockIdx.x * 64;
    const int tid = threadIdx.x, wid = tid >> 6, lane = tid & 63;
    const int lm = lane & 15, lk = lane >> 4;

    // Q fragments in registers (16 rows x 192, A-operand layout)
    short8 qf[6];
    const u16* qbase = Qb + ((long)h * 2048 + q0 + wid * 16 + lm) * 192;
#pragma unroll
    for (int kf = 0; kf < 6; ++kf) qf[kf] = *(const short8*)(qbase + kf * 32 + lk * 8);

    f32x4 o[8] = {};
    float mrow[4] = {-1e30f, -1e30f, -1e30f, -1e30f};
    float lrow[4] = {0.f, 0.f, 0.f, 0.f};

    const int nt = blockIdx.x + 1;
    for (int t = 0; t < nt; ++t) {
        const int k0 = t * 64;
        __syncthreads();
        // stage K tile: 64 x 192
#pragma unroll
        for (int i = 0; i < 6; ++i) {
            int v = i * 256 + tid;
            int r = v / 24, c = (v % 24) * 8;
            *(short8*)&Ks[r][c] = *(const short8*)(Kb + ((long)h * 2048 + k0 + r) * 192 + c);
        }
        // stage V transposed: 64 x 128 -> Vs[dv][kvrow]
#pragma unroll
        for (int i = 0; i < 4; ++i) {
            int v = i * 256 + tid;
            int r = v >> 4, c = (v & 15) * 8;
            short8 x = *(const short8*)(Vb + ((long)h * 2048 + k0 + r) * 128 + c);
#pragma unroll
            for (int j = 0; j < 8; ++j) Vs[c + j][r] = (u16)x[j];
        }
        __syncthreads();

        // S = Q K^T  (4 col-frags x 6 K-chunks)
        f32x4 sfr[4] = {};
#pragma unroll
        for (int n = 0; n < 4; ++n)
#pragma unroll
            for (int kf = 0; kf < 6; ++kf) {
                short8 kb = *(const short8*)&Ks[n * 16 + lm][kf * 32 + lk * 8];
                sfr[n] = __builtin_amdgcn_mfma_f32_16x16x32_bf16(qf[kf], kb, sfr[n], 0, 0, 0);
            }

        float sv[4][4];
        const bool bt = (t == nt - 1);
#pragma unroll
        for (int n = 0; n < 4; ++n)
#pragma unroll
            for (int r = 0; r < 4; ++r) {
                float val = sfr[n][r] * 0.07216878364870322f; // 192^-0.5
                if (bt && (k0 + n * 16 + lm > q0 + wid * 16 + lk * 4 + r)) val = -1e30f;
                sv[n][r] = val;
            }

        // online softmax (rows live in 16-lane groups)
#pragma unroll
        for (int r = 0; r < 4; ++r) {
            float mx = fmaxf(fmaxf(sv[0][r], sv[1][r]), fmaxf(sv[2][r], sv[3][r]));
#pragma unroll
            for (int off = 1; off < 16; off <<= 1) mx = fmaxf(mx, __shfl_xor(mx, off));
            float mnew = fmaxf(mrow[r], mx);
            float alpha = __expf(mrow[r] - mnew);
            mrow[r] = mnew;
            float psum = 0.f;
#pragma unroll
            for (int n = 0; n < 4; ++n) {
                float p = __expf(sv[n][r] - mnew);
                sv[n][r] = p;
                psum += p;
            }
#pragma unroll
            for (int off = 1; off < 16; off <<= 1) psum += __shfl_xor(psum, off);
            lrow[r] = lrow[r] * alpha + psum;
#pragma unroll
            for (int d = 0; d < 8; ++d) o[d][r] *= alpha;
        }

        // P -> LDS (bf16), per-wave region
#pragma unroll
        for (int n = 0; n < 4; ++n)
#pragma unroll
            for (int r = 0; r < 4; ++r)
                Ps[wid][lk * 4 + r][n * 16 + lm] = f2bf(sv[n][r]);
        __syncthreads();

        // O += P V
#pragma unroll
        for (int kc = 0; kc < 2; ++kc) {
            short8 pf = *(const short8*)&Ps[wid][lm][kc * 32 + lk * 8];
#pragma unroll
            for (int d = 0; d < 8; ++d) {
                short8 vf = *(const short8*)&Vs[d * 16 + lm][kc * 32 + lk * 8];
                o[d] = __builtin_amdgcn_mfma_f32_16x16x32_bf16(pf, vf, o[d], 0, 0, 0);
            }
        }
    }

    // epilogue: out[s][h*128+dv] = o / l
#pragma unroll
    for (int d = 0; d < 8; ++d)
#pragma unroll
        for (int r = 0; r < 4; ++r) {
            long row = q0 + wid * 16 + lk * 4 + r;
            Ao[row * 2048 + h * 128 + d * 16 + lm] = f2bf(o[d][r] / lrow[r]);
        }
}

// ---------------- host launch ----------------
extern "C" void kernel_launch(void* const* d_in, const int* in_sizes, int n_in,
                              void* d_out, int out_size, void* d_ws, size_t ws_size,
                              hipStream_t stream) {
    (void)in_sizes; (void)n_in; (void)out_size; (void)ws_size;
    const float* hidden  = (const float*)d_in[0];
    const float* q_a_w   = (const float*)d_in[1];
    const float* q_a_ln  = (const float*)d_in[2];
    const float* q_b_w   = (const float*)d_in[3];
    const float* kv_a_w  = (const float*)d_in[4];
    const float* kv_a_ln = (const float*)d_in[5];
    const float* kv_b_w  = (const float*)d_in[6];
    const float* o_w     = (const float*)d_in[7];
    const float* cosT    = (const float*)d_in[8];
    const float* sinT    = (const float*)d_in[9];
    const int*   pos     = (const int*)d_in[11];

    char* ws = (char*)d_ws;
    // persistent zone
    u16* o_w_bf   = (u16*)(ws + 0);          // 2048x2048
    u16* qb_w_bf  = (u16*)(ws + 8388608);    // 3072x1536
    u16* kvb_w_bf = (u16*)(ws + 17825792);   // 4096x512
    u16* qn_bf    = (u16*)(ws + 22020096);   // 2048x1536
    u16* kvn_bf   = (u16*)(ws + 28311552);   // 2048x512
    u16* Qb       = (u16*)(ws + 30408704);   // 16x2048x192
    u16* Kb       = (u16*)(ws + 42991616);   // 16x2048x192
    u16* Vb       = (u16*)(ws + 55574528);   // 16x2048x128
    u16* aout_bf  = (u16*)(ws + 63963136);   // 2048x2048
    // transient zone (reused)
    u16*   hid_bf   = (u16*)(ws + 72351744); // 2048x2048
    u16*   qa_w_bf  = (u16*)(ws + 80740352); // 1536x2048
    u16*   kva_w_bf = (u16*)(ws + 87031808); // 640x2048 (padded)
    float* qa_f     = (float*)(ws + 89653248);  // 2048x1536
    float* ckv_f    = (float*)(ws + 102236160); // 2048x640
    float* q_f      = (float*)(ws + 72351744);  // 2048x3072 (reuses hid/qa_w/qa_f after they die)
    float* kv_f     = (float*)(ws + 102236160); // 2048x4096 (reuses ckv after it dies)

    // converts
    conv_f32_bf16<<<(2048L*2048/4 + 255)/256, 256, 0, stream>>>(hidden, hid_bf, 2048L*2048/4);
    conv_f32_bf16<<<(1536L*2048/4 + 255)/256, 256, 0, stream>>>(q_a_w, qa_w_bf, 1536L*2048/4);
    conv_pad   <<<(640L*2048/4 + 255)/256, 256, 0, stream>>>(kv_a_w, kva_w_bf, 576, 640L*2048/4, 512);
    conv_f32_bf16<<<(3072L*1536/4 + 255)/256, 256, 0, stream>>>(q_b_w, qb_w_bf, 3072L*1536/4);
    conv_f32_bf16<<<(4096L*512/4 + 255)/256, 256, 0, stream>>>(kv_b_w, kvb_w_bf, 4096L*512/4);
    conv_f32_bf16<<<(2048L*2048/4 + 255)/256, 256, 0, stream>>>(o_w, o_w_bf, 2048L*2048/4);

    // down-projections
    gemm_bt<<<dim3(1536/128, 2048/128), 256, 0, stream>>>(hid_bf, qa_w_bf, qa_f, 2048, 1536, 2048);
    gemm_bt<<<dim3(640/128, 2048/128), 256, 0, stream>>>(hid_bf, kva_w_bf, ckv_f, 2048, 640, 2048);

    // norms + k_pe rope
    rmsnorm_bf16<<<2048, 256, 0, stream>>>(qa_f, q_a_ln, qn_bf, 1536, 1536, 1536);
    rmsnorm_bf16<<<2048, 256, 0, stream>>>(ckv_f, kv_a_ln, kvn_bf, 640, 512, 512);
    rope_k<<<(2048*32)/256, 256, 0, stream>>>(ckv_f, pos, cosT, sinT, Kb);

    // up-projections
    gemm_bt<<<dim3(3072/128, 2048/128), 256, 0, stream>>>(qn_bf, qb_w_bf, q_f, 2048, 3072, 1536);
    gemm_bt<<<dim3(4096/128, 2048/128), 256, 0, stream>>>(kvn_bf, kvb_w_bf, kv_f, 2048, 4096, 512);

    // assemble Q/K/V
    build_q<<<(unsigned)((16L*2048*192 + 255)/256), 256, 0, stream>>>(q_f, pos, cosT, sinT, Qb);
    build_kv<<<(unsigned)((16L*2048*256 + 255)/256), 256, 0, stream>>>(kv_f, Kb, Vb);

    // attention
    attn_fwd<<<dim3(32, 16), 256, 0, stream>>>(Qb, Kb, Vb, aout_bf);

    // output projection -> d_out (f32)
    gemm_bt<<<dim3(2048/128, 2048/128), 256, 0, stream>>>(aout_bf, o_w_bf, (float*)d_out, 2048, 2048, 2048);
}

// Round 2
// 360.762 us; speedup vs baseline: 1.3438x; 1.3438x over previous
//
#include <hip/hip_runtime.h>
#include <stdint.h>

typedef unsigned short u16;
typedef __attribute__((ext_vector_type(8))) short short8;
typedef __attribute__((ext_vector_type(4))) float f32x4;
typedef __attribute__((ext_vector_type(4))) unsigned short ushort4_t;
typedef __attribute__((ext_vector_type(4))) float float4_t;

#define DEV_INLINE __device__ __forceinline__

DEV_INLINE u16 f2bf(float f) {
    union { float f; unsigned u; } x; x.f = f;
    unsigned u = x.u;
    unsigned r = (u + 0x7FFFu + ((u >> 16) & 1u)) >> 16;
    return (u16)r;
}

// ---------------- convert kernels ----------------
__global__ void conv_f32_bf16(const float* __restrict__ in, u16* __restrict__ out, long n4) {
    long i = (long)blockIdx.x * blockDim.x + threadIdx.x;
    if (i >= n4) return;
    float4_t v = ((const float4_t*)in)[i];
    ushort4_t o;
    o.x = f2bf(v.x); o.y = f2bf(v.y); o.z = f2bf(v.z); o.w = f2bf(v.w);
    ((ushort4_t*)out)[i] = o;
}

__global__ void conv_pad(const float* __restrict__ in, u16* __restrict__ out,
                         int rows_valid, long n4, int cols4) {
    long i = (long)blockIdx.x * blockDim.x + threadIdx.x;
    if (i >= n4) return;
    long row = i / cols4;
    ushort4_t o; o.x = 0; o.y = 0; o.z = 0; o.w = 0;
    if (row < rows_valid) {
        float4_t v = ((const float4_t*)in)[i];
        o.x = f2bf(v.x); o.y = f2bf(v.y); o.z = f2bf(v.z); o.w = f2bf(v.w);
    }
    ((ushort4_t*)out)[i] = o;
}

// ---------------- GEMM: C[M,N] = A[M,K] * B[N,K]^T, bf16 in, f32 out ----------------
#define BM 128
#define BN 128
#define BK 32

DEV_INLINE void gload16(const u16* g, u16* l) {
    __builtin_amdgcn_global_load_lds((const __attribute__((address_space(1))) unsigned int*)g,
                                     (__attribute__((address_space(3))) unsigned int*)l,
                                     16, 0, 0);
}

__global__ __launch_bounds__(256) void gemm_bt(const u16* __restrict__ A, const u16* __restrict__ B,
                                               float* __restrict__ C, int M, int N, int K) {
    __shared__ u16 As[BM * BK];
    __shared__ u16 Bs[BN * BK];
    const int tid = threadIdx.x;
    const int wid = tid >> 6, lane = tid & 63;
    const int lm = lane & 15, lk = lane >> 4;
    const int wr = wid >> 1, wc = wid & 1;
    const long bm = (long)blockIdx.y * BM, bn = (long)blockIdx.x * BN;

    f32x4 acc[4][4] = {};

    const int rowS = lane >> 2;
    const int colS = (lane & 3) * 8;
    const u16* Ag = A + (bm + wid * 32 + rowS) * (long)K + colS;
    const u16* Bg = B + (bn + wid * 32 + rowS) * (long)K + colS;
    u16* AsW = &As[(wid * 32) * BK];
    u16* BsW = &Bs[(wid * 32) * BK];

    for (int k0 = 0; k0 < K; k0 += BK) {
        __syncthreads();
        gload16(Ag + k0, AsW);
        gload16(Ag + 16 * (long)K + k0, AsW + 16 * BK);
        gload16(Bg + k0, BsW);
        gload16(Bg + 16 * (long)K + k0, BsW + 16 * BK);
        __syncthreads();

        short8 af[4], bfr[4];
#pragma unroll
        for (int m = 0; m < 4; ++m)
            af[m] = *(const short8*)&As[(wr * 64 + m * 16 + lm) * BK + lk * 8];
#pragma unroll
        for (int n = 0; n < 4; ++n)
            bfr[n] = *(const short8*)&Bs[(wc * 64 + n * 16 + lm) * BK + lk * 8];
#pragma unroll
        for (int m = 0; m < 4; ++m)
#pragma unroll
            for (int n = 0; n < 4; ++n)
                acc[m][n] = __builtin_amdgcn_mfma_f32_16x16x32_bf16(af[m], bfr[n], acc[m][n], 0, 0, 0);
    }

#pragma unroll
    for (int m = 0; m < 4; ++m)
#pragma unroll
        for (int n = 0; n < 4; ++n)
#pragma unroll
            for (int r = 0; r < 4; ++r)
                C[(bm + wr * 64 + m * 16 + lk * 4 + r) * (long)N + bn + wc * 64 + n * 16 + lm] = acc[m][n][r];
}

// ---------------- RMSNorm (f32 in, bf16 out) ----------------
__global__ __launch_bounds__(256) void rmsnorm_bf16(const float* __restrict__ in, const float* __restrict__ w,
                                                    u16* __restrict__ out, int ldin, int ldout, int ncols) {
    const int row = blockIdx.x, tid = threadIdx.x;
    const float* x = in + (long)row * ldin;
    float ss = 0.f;
    for (int c = tid; c < ncols; c += 256) { float v = x[c]; ss = fmaf(v, v, ss); }
#pragma unroll
    for (int off = 32; off > 0; off >>= 1) ss += __shfl_down(ss, off);
    __shared__ float part[4];
    if ((tid & 63) == 0) part[tid >> 6] = ss;
    __syncthreads();
    float tot = part[0] + part[1] + part[2] + part[3];
    float rs = rsqrtf(tot / (float)ncols + 1e-6f);
    for (int c = tid; c < ncols; c += 256) out[(long)row * ldout + c] = f2bf(x[c] * rs * w[c]);
}

// ---------------- k_pe RoPE -> K[:, :, 128:192] for all heads ----------------
__global__ void rope_k(const float* __restrict__ ckv, const int* __restrict__ pos,
                       const float* __restrict__ cosT, const float* __restrict__ sinT,
                       u16* __restrict__ Kb) {
    int idx = blockIdx.x * 256 + threadIdx.x;
    if (idx >= 2048 * 32) return;
    int s = idx >> 5, j = idx & 31;
    long p = pos[s];
    const float* row = ckv + (long)s * 640 + 512;
    float x0 = row[2 * j], x1 = row[2 * j + 1];
    float c0 = cosT[p * 64 + j],      s0 = sinT[p * 64 + j];
    float c1 = cosT[p * 64 + 32 + j], s1 = sinT[p * 64 + 32 + j];
    u16 o0 = f2bf(x0 * c0 - x1 * s0);
    u16 o1 = f2bf(x1 * c1 + x0 * s1);
#pragma unroll
    for (int h = 0; h < 16; ++h) {
        u16* kr = Kb + ((long)h * 2048 + s) * 192 + 128;
        kr[j] = o0; kr[32 + j] = o1;
    }
}

// ---------------- assemble Q (with RoPE on last 64 dims) ----------------
__global__ void build_q(const float* __restrict__ q, const int* __restrict__ pos,
                        const float* __restrict__ cosT, const float* __restrict__ sinT,
                        u16* __restrict__ Qb) {
    long idx = (long)blockIdx.x * 256 + threadIdx.x;
    if (idx >= 16L * 2048 * 192) return;
    int d = (int)(idx % 192);
    int s = (int)((idx / 192) % 2048);
    int h = (int)(idx / (192L * 2048));
    const float* qrow = q + (long)s * 3072 + h * 192;
    float val;
    if (d < 128) {
        val = qrow[d];
    } else {
        long p = pos[s];
        int dd = d - 128;
        float cv = cosT[p * 64 + dd], sv = sinT[p * 64 + dd];
        if (dd < 32) val = qrow[128 + 2 * dd] * cv - qrow[128 + 2 * dd + 1] * sv;
        else { int jj = dd - 32; val = qrow[128 + 2 * jj + 1] * cv + qrow[128 + 2 * jj] * sv; }
    }
    Qb[((long)h * 2048 + s) * 192 + d] = f2bf(val);
}

// ---------------- K assembly (nope part only) ----------------
__global__ void build_k(const float* __restrict__ kv, u16* __restrict__ Kb) {
    long idx = (long)blockIdx.x * 256 + threadIdx.x;
    if (idx >= 16L * 2048 * 128) return;
    int d = (int)(idx & 127);
    int s = (int)((idx >> 7) & 2047);
    int h = (int)(idx >> 18);
    Kb[((long)h * 2048 + s) * 192 + d] = f2bf(kv[(long)s * 4096 + h * 256 + d]);
}

// ---------------- V transpose: kv_f[s][h*256+128+d] -> Vt[h][d][s] (bf16) ----------------
__global__ __launch_bounds__(256) void vtrans(const float* __restrict__ kv, u16* __restrict__ Vt) {
    __shared__ u16 Ls[64][68];
    const int s0 = blockIdx.x * 64, d0 = blockIdx.y * 64, h = blockIdx.z;
    const int tid = threadIdx.x;
#pragma unroll
    for (int i = 0; i < 16; ++i) {
        int idx = i * 256 + tid;
        int sl = idx >> 6, dl = idx & 63;
        Ls[dl][sl] = f2bf(kv[(long)(s0 + sl) * 4096 + h * 256 + 128 + d0 + dl]);
    }
    __syncthreads();
#pragma unroll
    for (int i = 0; i < 16; ++i) {
        int idx = i * 256 + tid;
        int dl = idx >> 6, sl = idx & 63;
        Vt[((long)h * 128 + d0 + dl) * 2048 + s0 + sl] = Ls[dl][sl];
    }
}

// ---------------- causal flash attention, pair-balanced ----------------
// Q,K: [H][S][192] bf16, Vt: [H][128][S] bf16 (V transposed), out: [S][H*128] bf16
// block b: head h = (b&7)*2 + ((b>>3)&1)  (2 heads/XCD for L2 locality),
//          pair pi = b>>4: processes q-tiles pi and 31-pi sequentially (33 kv-tiles total)
__global__ __launch_bounds__(256) void attn_fwd(const u16* __restrict__ Qb, const u16* __restrict__ Kb,
                                                const u16* __restrict__ Vt, u16* __restrict__ Ao) {
    __shared__ u16 Ks[64][200];   // row stride 400B == 16 mod 128 -> conflict-free b128 reads
    __shared__ u16 Vs[8192];      // off(dv,kvb) = kvb*1024 + ((dv*8)^(kvb*16)); bank-uniform
    __shared__ u16 Ps[4][16][72]; // per-wave P tile

    const int b = blockIdx.x;
    const int h = (b & 7) * 2 + ((b >> 3) & 1);
    const int pi = b >> 4;
    const int tid = threadIdx.x, wid = tid >> 6, lane = tid & 63;
    const int lm = lane & 15, lk = lane >> 4;

    const u16* Kh = Kb + (long)h * 2048 * 192;
    const u16* Vh = Vt + (long)h * 128 * 2048;

    for (int half = 0; half < 2; ++half) {
        const int qi = half ? (31 - pi) : pi;
        const int q0 = qi * 64;
        const int ntile = qi + 1;

        // Q fragments in registers (16 rows x 192 per wave)
        short8 qf[6];
        const u16* qbase = Qb + ((long)h * 2048 + q0 + wid * 16 + lm) * 192;
#pragma unroll
        for (int kf = 0; kf < 6; ++kf) qf[kf] = *(const short8*)(qbase + kf * 32 + lk * 8);

        f32x4 o[8] = {};
        float mrow[4] = {-1e30f, -1e30f, -1e30f, -1e30f};
        float lrow[4] = {0.f, 0.f, 0.f, 0.f};

        short8 kreg[6], vreg[4];
        // prologue: stage tile 0
        {
            const long koff = 0;
#pragma unroll
            for (int i = 0; i < 6; ++i)
                kreg[i] = *(const short8*)(Kh + koff * 192 + (i * 256 + tid) * 8);
#pragma unroll
            for (int i = 0; i < 4; ++i) {
                int idx = i * 256 + tid; int dv = idx >> 3, kvb = idx & 7;
                vreg[i] = *(const short8*)(Vh + (long)dv * 2048 + koff + kvb * 8);
            }
#pragma unroll
            for (int i = 0; i < 6; ++i) {
                int v = i * 256 + tid; int r = v / 24, c = (v % 24) * 8;
                *(short8*)&Ks[r][c] = kreg[i];
            }
#pragma unroll
            for (int i = 0; i < 4; ++i) {
                int idx = i * 256 + tid; int dv = idx >> 3, kvb = idx & 7;
                *(short8*)&Vs[kvb * 1024 + ((dv * 8) ^ (kvb * 16))] = vreg[i];
            }
        }
        __syncthreads();

        for (int t = 0; t < ntile; ++t) {
            const int k0 = t * 64;
            const bool more = (t + 1 < ntile);
            // issue next tile's global loads early (latency hides under compute)
            if (more) {
                const long koff = (long)(t + 1) * 64;
#pragma unroll
                for (int i = 0; i < 6; ++i)
                    kreg[i] = *(const short8*)(Kh + koff * 192 + (i * 256 + tid) * 8);
#pragma unroll
                for (int i = 0; i < 4; ++i) {
                    int idx = i * 256 + tid; int dv = idx >> 3, kvb = idx & 7;
                    vreg[i] = *(const short8*)(Vh + (long)dv * 2048 + koff + kvb * 8);
                }
            }

            // S = Q K^T
            f32x4 sfr[4] = {};
#pragma unroll
            for (int n = 0; n < 4; ++n)
#pragma unroll
                for (int kf = 0; kf < 6; ++kf) {
                    short8 kb = *(const short8*)&Ks[n * 16 + lm][kf * 32 + lk * 8];
                    sfr[n] = __builtin_amdgcn_mfma_f32_16x16x32_bf16(qf[kf], kb, sfr[n], 0, 0, 0);
                }

            float sv[4][4];
            const bool bt = (t == ntile - 1);
#pragma unroll
            for (int n = 0; n < 4; ++n)
#pragma unroll
                for (int r = 0; r < 4; ++r) {
                    float val = sfr[n][r] * 0.07216878364870322f; // 192^-0.5
                    if (bt && (k0 + n * 16 + lm > q0 + wid * 16 + lk * 4 + r)) val = -1e30f;
                    sv[n][r] = val;
                }

            // online softmax (rows live in 16-lane groups)
#pragma unroll
            for (int r = 0; r < 4; ++r) {
                float mx = fmaxf(fmaxf(sv[0][r], sv[1][r]), fmaxf(sv[2][r], sv[3][r]));
#pragma unroll
                for (int off = 1; off < 16; off <<= 1) mx = fmaxf(mx, __shfl_xor(mx, off));
                float mnew = fmaxf(mrow[r], mx);
                float alpha = __expf(mrow[r] - mnew);
                mrow[r] = mnew;
                float psum = 0.f;
#pragma unroll
                for (int n = 0; n < 4; ++n) {
                    float p = __expf(sv[n][r] - mnew);
                    sv[n][r] = p;
                    psum += p;
                }
#pragma unroll
                for (int off = 1; off < 16; off <<= 1) psum += __shfl_xor(psum, off);
                lrow[r] = lrow[r] * alpha + psum;
#pragma unroll
                for (int d = 0; d < 8; ++d) o[d][r] *= alpha;
            }

            // P -> LDS (per-wave region, no cross-wave barrier needed)
#pragma unroll
            for (int n = 0; n < 4; ++n)
#pragma unroll
                for (int r = 0; r < 4; ++r)
                    Ps[wid][lk * 4 + r][n * 16 + lm] = f2bf(sv[n][r]);

            // O += P V
#pragma unroll
            for (int kc = 0; kc < 2; ++kc) {
                short8 pf = *(const short8*)&Ps[wid][lm][kc * 32 + lk * 8];
#pragma unroll
                for (int d = 0; d < 8; ++d) {
                    int kvb = kc * 4 + lk;
                    short8 vf = *(const short8*)&Vs[kvb * 1024 + (((d * 16 + lm) * 8) ^ (kvb * 16))];
                    o[d] = __builtin_amdgcn_mfma_f32_16x16x32_bf16(pf, vf, o[d], 0, 0, 0);
                }
            }

            __syncthreads();   // all waves done reading Ks/Vs of tile t
            if (more) {
#pragma unroll
                for (int i = 0; i < 6; ++i) {
                    int v = i * 256 + tid; int r = v / 24, c = (v % 24) * 8;
                    *(short8*)&Ks[r][c] = kreg[i];
                }
#pragma unroll
                for (int i = 0; i < 4; ++i) {
                    int idx = i * 256 + tid; int dv = idx >> 3, kvb = idx & 7;
                    *(short8*)&Vs[kvb * 1024 + ((dv * 8) ^ (kvb * 16))] = vreg[i];
                }
            }
            __syncthreads();   // staged tile t+1 visible
        }

        // epilogue
#pragma unroll
        for (int d = 0; d < 8; ++d)
#pragma unroll
            for (int r = 0; r < 4; ++r) {
                long row = q0 + wid * 16 + lk * 4 + r;
                Ao[row * 2048 + h * 128 + d * 16 + lm] = f2bf(o[d][r] / lrow[r]);
            }
    }
}

// ---------------- host launch ----------------
extern "C" void kernel_launch(void* const* d_in, const int* in_sizes, int n_in,
                              void* d_out, int out_size, void* d_ws, size_t ws_size,
                              hipStream_t stream) {
    (void)in_sizes; (void)n_in; (void)out_size; (void)ws_size;
    const float* hidden  = (const float*)d_in[0];
    const float* q_a_w   = (const float*)d_in[1];
    const float* q_a_ln  = (const float*)d_in[2];
    const float* q_b_w   = (const float*)d_in[3];
    const float* kv_a_w  = (const float*)d_in[4];
    const float* kv_a_ln = (const float*)d_in[5];
    const float* kv_b_w  = (const float*)d_in[6];
    const float* o_w     = (const float*)d_in[7];
    const float* cosT    = (const float*)d_in[8];
    const float* sinT    = (const float*)d_in[9];
    const int*   pos     = (const int*)d_in[11];

    char* ws = (char*)d_ws;
    // persistent zone
    u16* o_w_bf   = (u16*)(ws + 0);          // 2048x2048
    u16* qb_w_bf  = (u16*)(ws + 8388608);    // 3072x1536
    u16* kvb_w_bf = (u16*)(ws + 17825792);   // 4096x512
    u16* qn_bf    = (u16*)(ws + 22020096);   // 2048x1536
    u16* kvn_bf   = (u16*)(ws + 28311552);   // 2048x512
    u16* Qb       = (u16*)(ws + 30408704);   // 16x2048x192
    u16* Kb       = (u16*)(ws + 42991616);   // 16x2048x192
    u16* Vt       = (u16*)(ws + 55574528);   // 16x128x2048 (V transposed)
    u16* aout_bf  = (u16*)(ws + 63963136);   // 2048x2048
    // transient zone (reused)
    u16*   hid_bf   = (u16*)(ws + 72351744); // 2048x2048
    u16*   qa_w_bf  = (u16*)(ws + 80740352); // 1536x2048
    u16*   kva_w_bf = (u16*)(ws + 87031808); // 640x2048 (padded)
    float* qa_f     = (float*)(ws + 89653248);  // 2048x1536
    float* ckv_f    = (float*)(ws + 102236160); // 2048x640
    float* q_f      = (float*)(ws + 72351744);  // 2048x3072 (reuses hid/qa_w/qa_f)
    float* kv_f     = (float*)(ws + 102236160); // 2048x4096 (reuses ckv)

    // converts
    conv_f32_bf16<<<(2048L*2048/4 + 255)/256, 256, 0, stream>>>(hidden, hid_bf, 2048L*2048/4);
    conv_f32_bf16<<<(1536L*2048/4 + 255)/256, 256, 0, stream>>>(q_a_w, qa_w_bf, 1536L*2048/4);
    conv_pad   <<<(640L*2048/4 + 255)/256, 256, 0, stream>>>(kv_a_w, kva_w_bf, 576, 640L*2048/4, 512);
    conv_f32_bf16<<<(3072L*1536/4 + 255)/256, 256, 0, stream>>>(q_b_w, qb_w_bf, 3072L*1536/4);
    conv_f32_bf16<<<(4096L*512/4 + 255)/256, 256, 0, stream>>>(kv_b_w, kvb_w_bf, 4096L*512/4);
    conv_f32_bf16<<<(2048L*2048/4 + 255)/256, 256, 0, stream>>>(o_w, o_w_bf, 2048L*2048/4);

    // down-projections
    gemm_bt<<<dim3(1536/128, 2048/128), 256, 0, stream>>>(hid_bf, qa_w_bf, qa_f, 2048, 1536, 2048);
    gemm_bt<<<dim3(640/128, 2048/128), 256, 0, stream>>>(hid_bf, kva_w_bf, ckv_f, 2048, 640, 2048);

    // norms + k_pe rope
    rmsnorm_bf16<<<2048, 256, 0, stream>>>(qa_f, q_a_ln, qn_bf, 1536, 1536, 1536);
    rmsnorm_bf16<<<2048, 256, 0, stream>>>(ckv_f, kv_a_ln, kvn_bf, 640, 512, 512);
    rope_k<<<(2048*32)/256, 256, 0, stream>>>(ckv_f, pos, cosT, sinT, Kb);

    // up-projections
    gemm_bt<<<dim3(3072/128, 2048/128), 256, 0, stream>>>(qn_bf, qb_w_bf, q_f, 2048, 3072, 1536);
    gemm_bt<<<dim3(4096/128, 2048/128), 256, 0, stream>>>(kvn_bf, kvb_w_bf, kv_f, 2048, 4096, 512);

    // assemble Q/K/V
    build_q<<<(unsigned)((16L*2048*192 + 255)/256), 256, 0, stream>>>(q_f, pos, cosT, sinT, Qb);
    build_k<<<(unsigned)((16L*2048*128 + 255)/256), 256, 0, stream>>>(kv_f, Kb);
    vtrans<<<dim3(32, 2, 16), 256, 0, stream>>>(kv_f, Vt);

    // attention (256 balanced blocks)
    attn_fwd<<<256, 256, 0, stream>>>(Qb, Kb, Vt, aout_bf);

    // output projection -> d_out (f32)
    gemm_bt<<<dim3(2048/128, 2048/128), 256, 0, stream>>>(aout_bf, o_w_bf, (float*)d_out, 2048, 2048, 2048);
}

// Round 3
// 280.658 us; speedup vs baseline: 1.7273x; 1.2854x over previous
//
#include <hip/hip_runtime.h>
#include <stdint.h>

typedef unsigned short u16;
typedef __attribute__((ext_vector_type(8))) short short8;
typedef __attribute__((ext_vector_type(4))) float f32x4;
typedef __attribute__((ext_vector_type(4))) unsigned short ushort4_t;
typedef __attribute__((ext_vector_type(4))) float float4_t;

#define DEV_INLINE __device__ __forceinline__

DEV_INLINE u16 f2bf(float f) {
    union { float f; unsigned u; } x; x.f = f;
    unsigned u = x.u;
    unsigned r = (u + 0x7FFFu + ((u >> 16) & 1u)) >> 16;
    return (u16)r;
}

DEV_INLINE float fexp2(float x) {
    float r;
    asm("v_exp_f32 %0, %1" : "=v"(r) : "v"(x));
    return r;
}

// ---------------- convert kernels ----------------
__global__ void conv_f32_bf16(const float* __restrict__ in, u16* __restrict__ out, long n4) {
    long i = (long)blockIdx.x * blockDim.x + threadIdx.x;
    if (i >= n4) return;
    float4_t v = ((const float4_t*)in)[i];
    ushort4_t o;
    o.x = f2bf(v.x); o.y = f2bf(v.y); o.z = f2bf(v.z); o.w = f2bf(v.w);
    ((ushort4_t*)out)[i] = o;
}

__global__ void conv_pad(const float* __restrict__ in, u16* __restrict__ out,
                         int rows_valid, long n4, int cols4) {
    long i = (long)blockIdx.x * blockDim.x + threadIdx.x;
    if (i >= n4) return;
    long row = i / cols4;
    ushort4_t o; o.x = 0; o.y = 0; o.z = 0; o.w = 0;
    if (row < rows_valid) {
        float4_t v = ((const float4_t*)in)[i];
        o.x = f2bf(v.x); o.y = f2bf(v.y); o.z = f2bf(v.z); o.w = f2bf(v.w);
    }
    ((ushort4_t*)out)[i] = o;
}

// ---------------- GEMM (BM=128): C[M,N] = A[M,K] * B[N,K]^T ----------------
#define BK 32

DEV_INLINE void gload16(const u16* g, u16* l) {
    __builtin_amdgcn_global_load_lds((const __attribute__((address_space(1))) unsigned int*)g,
                                     (__attribute__((address_space(3))) unsigned int*)l,
                                     16, 0, 0);
}

__global__ __launch_bounds__(256) void gemm_bt(const u16* __restrict__ A, const u16* __restrict__ B,
                                               float* __restrict__ C, int M, int N, int K) {
    __shared__ u16 As[128 * BK];
    __shared__ u16 Bs[128 * BK];
    const int tid = threadIdx.x;
    const int wid = tid >> 6, lane = tid & 63;
    const int lm = lane & 15, lk = lane >> 4;
    const int wr = wid >> 1, wc = wid & 1;
    const long bm = (long)blockIdx.y * 128, bn = (long)blockIdx.x * 128;

    f32x4 acc[4][4] = {};

    const int rowS = lane >> 2;
    const int colS = ((lane & 3) ^ ((lane >> 3) & 3)) * 8;   // swizzled source col
    const int cs = (lm >> 1) & 3;                            // frag-read XOR
    const u16* Ag = A + (bm + wid * 32 + rowS) * (long)K + colS;
    const u16* Bg = B + (bn + wid * 32 + rowS) * (long)K + colS;
    u16* AsW = &As[(wid * 32) * BK];
    u16* BsW = &Bs[(wid * 32) * BK];

    for (int k0 = 0; k0 < K; k0 += BK) {
        __syncthreads();
        gload16(Ag + k0, AsW);
        gload16(Ag + 16 * (long)K + k0, AsW + 16 * BK);
        gload16(Bg + k0, BsW);
        gload16(Bg + 16 * (long)K + k0, BsW + 16 * BK);
        __syncthreads();

        short8 af[4], bfr[4];
#pragma unroll
        for (int m = 0; m < 4; ++m)
            af[m] = *(const short8*)&As[(wr * 64 + m * 16 + lm) * BK + (lk ^ cs) * 8];
#pragma unroll
        for (int n = 0; n < 4; ++n)
            bfr[n] = *(const short8*)&Bs[(wc * 64 + n * 16 + lm) * BK + (lk ^ cs) * 8];
#pragma unroll
        for (int m = 0; m < 4; ++m)
#pragma unroll
            for (int n = 0; n < 4; ++n)
                acc[m][n] = __builtin_amdgcn_mfma_f32_16x16x32_bf16(af[m], bfr[n], acc[m][n], 0, 0, 0);
    }

#pragma unroll
    for (int m = 0; m < 4; ++m)
#pragma unroll
        for (int n = 0; n < 4; ++n)
#pragma unroll
            for (int r = 0; r < 4; ++r)
                C[(bm + wr * 64 + m * 16 + lk * 4 + r) * (long)N + bn + wc * 64 + n * 16 + lm] = acc[m][n][r];
}

// ---------------- GEMM (BM=64): more blocks for small grids ----------------
__global__ __launch_bounds__(256) void gemm_bt64(const u16* __restrict__ A, const u16* __restrict__ B,
                                                 float* __restrict__ C, int M, int N, int K) {
    __shared__ u16 As[64 * BK];
    __shared__ u16 Bs[128 * BK];
    const int tid = threadIdx.x;
    const int wid = tid >> 6, lane = tid & 63;
    const int lm = lane & 15, lk = lane >> 4;
    const long bm = (long)blockIdx.y * 64, bn = (long)blockIdx.x * 128;

    f32x4 acc[4][2] = {};

    const int rowS = lane >> 2;
    const int colS = ((lane & 3) ^ ((lane >> 3) & 3)) * 8;
    const int cs = (lm >> 1) & 3;
    const u16* Ag = A + (bm + wid * 16 + rowS) * (long)K + colS;
    const u16* Bg = B + (bn + wid * 32 + rowS) * (long)K + colS;
    u16* AsW = &As[(wid * 16) * BK];
    u16* BsW = &Bs[(wid * 32) * BK];

    for (int k0 = 0; k0 < K; k0 += BK) {
        __syncthreads();
        gload16(Ag + k0, AsW);
        gload16(Bg + k0, BsW);
        gload16(Bg + 16 * (long)K + k0, BsW + 16 * BK);
        __syncthreads();

        short8 af[4], bfr[2];
#pragma unroll
        for (int m = 0; m < 4; ++m)
            af[m] = *(const short8*)&As[(m * 16 + lm) * BK + (lk ^ cs) * 8];
#pragma unroll
        for (int n = 0; n < 2; ++n)
            bfr[n] = *(const short8*)&Bs[(wid * 32 + n * 16 + lm) * BK + (lk ^ cs) * 8];
#pragma unroll
        for (int m = 0; m < 4; ++m)
#pragma unroll
            for (int n = 0; n < 2; ++n)
                acc[m][n] = __builtin_amdgcn_mfma_f32_16x16x32_bf16(af[m], bfr[n], acc[m][n], 0, 0, 0);
    }

#pragma unroll
    for (int m = 0; m < 4; ++m)
#pragma unroll
        for (int n = 0; n < 2; ++n)
#pragma unroll
            for (int r = 0; r < 4; ++r)
                C[(bm + m * 16 + lk * 4 + r) * (long)N + bn + wid * 32 + n * 16 + lm] = acc[m][n][r];
}

// ---------------- RMSNorm (f32 in, bf16 out) ----------------
__global__ __launch_bounds__(256) void rmsnorm_bf16(const float* __restrict__ in, const float* __restrict__ w,
                                                    u16* __restrict__ out, int ldin, int ldout, int ncols) {
    const int row = blockIdx.x, tid = threadIdx.x;
    const float* x = in + (long)row * ldin;
    float ss = 0.f;
    for (int c = tid; c < ncols; c += 256) { float v = x[c]; ss = fmaf(v, v, ss); }
#pragma unroll
    for (int off = 32; off > 0; off >>= 1) ss += __shfl_down(ss, off);
    __shared__ float part[4];
    if ((tid & 63) == 0) part[tid >> 6] = ss;
    __syncthreads();
    float tot = part[0] + part[1] + part[2] + part[3];
    float rs = rsqrtf(tot / (float)ncols + 1e-6f);
    for (int c = tid; c < ncols; c += 256) out[(long)row * ldout + c] = f2bf(x[c] * rs * w[c]);
}

// ---------------- k_pe RoPE -> K[:, :, 128:192] for all heads ----------------
__global__ void rope_k(const float* __restrict__ ckv, const int* __restrict__ pos,
                       const float* __restrict__ cosT, const float* __restrict__ sinT,
                       u16* __restrict__ Kb) {
    int idx = blockIdx.x * 256 + threadIdx.x;
    if (idx >= 2048 * 32) return;
    int s = idx >> 5, j = idx & 31;
    long p = pos[s];
    const float* row = ckv + (long)s * 2176 + 2048;   // combined buffer, k_pe at col 2048
    float x0 = row[2 * j], x1 = row[2 * j + 1];
    float c0 = cosT[p * 64 + j],      s0 = sinT[p * 64 + j];
    float c1 = cosT[p * 64 + 32 + j], s1 = sinT[p * 64 + 32 + j];
    u16 o0 = f2bf(x0 * c0 - x1 * s0);
    u16 o1 = f2bf(x1 * c1 + x0 * s1);
#pragma unroll
    for (int h = 0; h < 16; ++h) {
        u16* kr = Kb + ((long)h * 2048 + s) * 192 + 128;
        kr[j] = o0; kr[32 + j] = o1;
    }
}

// ---------------- assemble Q (with RoPE on last 64 dims) ----------------
__global__ void build_q(const float* __restrict__ q, const int* __restrict__ pos,
                        const float* __restrict__ cosT, const float* __restrict__ sinT,
                        u16* __restrict__ Qb) {
    long idx = (long)blockIdx.x * 256 + threadIdx.x;
    if (idx >= 16L * 2048 * 192) return;
    int d = (int)(idx % 192);
    int s = (int)((idx / 192) % 2048);
    int h = (int)(idx / (192L * 2048));
    const float* qrow = q + (long)s * 3072 + h * 192;
    float val;
    if (d < 128) {
        val = qrow[d];
    } else {
        long p = pos[s];
        int dd = d - 128;
        float cv = cosT[p * 64 + dd], sv = sinT[p * 64 + dd];
        if (dd < 32) val = qrow[128 + 2 * dd] * cv - qrow[128 + 2 * dd + 1] * sv;
        else { int jj = dd - 32; val = qrow[128 + 2 * jj + 1] * cv + qrow[128 + 2 * jj] * sv; }
    }
    Qb[((long)h * 2048 + s) * 192 + d] = f2bf(val);
}

// ---------------- K assembly (nope part only) ----------------
__global__ void build_k(const float* __restrict__ kv, u16* __restrict__ Kb) {
    long idx = (long)blockIdx.x * 256 + threadIdx.x;
    if (idx >= 16L * 2048 * 128) return;
    int d = (int)(idx & 127);
    int s = (int)((idx >> 7) & 2047);
    int h = (int)(idx >> 18);
    Kb[((long)h * 2048 + s) * 192 + d] = f2bf(kv[(long)s * 4096 + h * 256 + d]);
}

// ---------------- V transpose: kv_f[s][h*256+128+d] -> Vt[h][d][s] (bf16) ----------------
__global__ __launch_bounds__(256) void vtrans(const float* __restrict__ kv, u16* __restrict__ Vt) {
    __shared__ u16 Ls[64][68];
    const int s0 = blockIdx.x * 64, d0 = blockIdx.y * 64, h = blockIdx.z;
    const int tid = threadIdx.x;
#pragma unroll
    for (int i = 0; i < 16; ++i) {
        int idx = i * 256 + tid;
        int sl = idx >> 6, dl = idx & 63;
        Ls[dl][sl] = f2bf(kv[(long)(s0 + sl) * 4096 + h * 256 + 128 + d0 + dl]);
    }
    __syncthreads();
#pragma unroll
    for (int i = 0; i < 16; ++i) {
        int idx = i * 256 + tid;
        int dl = idx >> 6, sl = idx & 63;
        Vt[((long)h * 128 + d0 + dl) * 2048 + s0 + sl] = Ls[dl][sl];
    }
}

// ---------------- causal flash attention: 8-wave in-block KV split ----------------
// Q,K: [H][S][192] bf16, Vt: [H][128][S] bf16, out: [S][H*128] bf16
// 256 blocks x 512 thr. Block b: head h=(b&7)*2+((b>>3)&1), pair pi=b>>4.
// Halves: q-tiles pi and 31-pi (64 rows each). KV tiles of 32 rows; waves 0-3
// take even tiles, 4-7 odd tiles (nt=2qi+2 always even -> uniform loops).
// Partials combined through LDS at the end of each half.
__global__ __launch_bounds__(512, 2) void attn_fwd(const u16* __restrict__ Qb, const u16* __restrict__ Kb,
                                                   const u16* __restrict__ Vt, u16* __restrict__ Ao) {
    // smem layout:
    //  [0,25600):       Ks[2][32][200] u16   (per-split K tile, stride 200 breaks conflicts)
    //  [25600,41984):   Vs[2][4096] u16      (per-split V^T, XOR-swizzled)
    //  Ob alias [0,32768): float[4][16][128] (combine buffer, reuses Ks+Vs)
    //  [41984,52224):   Ps[8][16][40] u16    (per-wave P tile)
    //  [52224,52736):   ML float[4][16][2]
    __shared__ __align__(16) char smem[52736];

    const int b = blockIdx.x;
    const int h = (b & 7) * 2 + ((b >> 3) & 1);
    const int pi = b >> 4;
    const int tid = threadIdx.x;
    const int wid = tid >> 6, lane = tid & 63;
    const int lm = lane & 15, lk = lane >> 4;
    const int s = wid >> 2;          // split (0: even tiles, 1: odd tiles)
    const int wp = wid & 3;          // wave-pair index (16-row group)
    const int t256 = tid & 255;

    u16* KsS = (u16*)(smem) + s * 6400;
    u16* VsS = (u16*)(smem + 25600) + s * 4096;
    u16* PsW = (u16*)(smem + 41984) + wid * 640;
    float* ML = (float*)(smem + 52224);
    float* Ob = (float*)smem;

    const u16* Kh = Kb + (long)h * 2048 * 192;
    const u16* Vh = Vt + (long)h * 128 * 2048;

    short8 bones = {};
    if (lm == 0) {
#pragma unroll
        for (int j = 0; j < 8; ++j) bones[j] = (short)0x3F80;   // bf16 1.0
    }
    const float C2 = 0.104117548f;   // 192^-0.5 * log2(e)

    for (int half = 0; half < 2; ++half) {
        const int qi = half ? (31 - pi) : pi;
        const int q0 = qi * 64;
        const int nt = 2 * qi + 2;
        const int niter = qi + 1;

        short8 qf[6];
        const u16* qbase = Qb + ((long)h * 2048 + q0 + wp * 16 + lm) * 192;
#pragma unroll
        for (int kf = 0; kf < 6; ++kf) qf[kf] = *(const short8*)(qbase + kf * 32 + lk * 8);

        f32x4 o[8] = {};
        f32x4 o9 = {};
        float mrow[4] = {-1e30f, -1e30f, -1e30f, -1e30f};

        short8 kreg[3], vreg[2];
        // prologue: stage tile index s
        {
            const long k0 = s * 32;
#pragma unroll
            for (int i = 0; i < 3; ++i) {
                int idx = i * 256 + t256; int r = idx / 24, c = (idx % 24) * 8;
                kreg[i] = *(const short8*)(Kh + (k0 + r) * 192 + c);
            }
#pragma unroll
            for (int i = 0; i < 2; ++i) {
                int idx = i * 256 + t256; int dv = idx >> 2, kvb = idx & 3;
                vreg[i] = *(const short8*)(Vh + (long)dv * 2048 + k0 + kvb * 8);
            }
#pragma unroll
            for (int i = 0; i < 3; ++i) {
                int idx = i * 256 + t256; int r = idx / 24, c = (idx % 24) * 8;
                *(short8*)&KsS[r * 200 + c] = kreg[i];
            }
#pragma unroll
            for (int i = 0; i < 2; ++i) {
                int idx = i * 256 + t256; int dv = idx >> 2, kvb = idx & 3;
                *(short8*)&VsS[kvb * 1024 + ((dv * 8) ^ (kvb * 16))] = vreg[i];
            }
        }
        __syncthreads();

        for (int it = 0; it < niter; ++it) {
            const int ts = 2 * it + s;
            const int k0 = ts * 32;
            const bool more = (it + 1 < niter);

            if (more) {
                const long k0n = (long)(2 * (it + 1) + s) * 32;
#pragma unroll
                for (int i = 0; i < 3; ++i) {
                    int idx = i * 256 + t256; int r = idx / 24, c = (idx % 24) * 8;
                    kreg[i] = *(const short8*)(Kh + (k0n + r) * 192 + c);
                }
#pragma unroll
                for (int i = 0; i < 2; ++i) {
                    int idx = i * 256 + t256; int dv = idx >> 2, kvb = idx & 3;
                    vreg[i] = *(const short8*)(Vh + (long)dv * 2048 + k0n + kvb * 8);
                }
            }

            // S = Q K^T  (16 q-rows x 32 kv)
            f32x4 sfr[2] = {};
#pragma unroll
            for (int n = 0; n < 2; ++n)
#pragma unroll
                for (int kf = 0; kf < 6; ++kf) {
                    short8 kb = *(const short8*)&KsS[(n * 16 + lm) * 200 + kf * 32 + lk * 8];
                    sfr[n] = __builtin_amdgcn_mfma_f32_16x16x32_bf16(qf[kf], kb, sfr[n], 0, 0, 0);
                }

            float sv[2][4];
            const bool bt = (ts >= nt - 2);   // two 32-tiles straddle the diagonal
#pragma unroll
            for (int n = 0; n < 2; ++n)
#pragma unroll
                for (int r = 0; r < 4; ++r) {
                    float val = sfr[n][r] * C2;
                    if (bt && (k0 + n * 16 + lm > q0 + wp * 16 + lk * 4 + r)) val = -1e30f;
                    sv[n][r] = val;
                }

            // online softmax (base-2), deferred-max rescale
            float pmax[4];
#pragma unroll
            for (int r = 0; r < 4; ++r) {
                float mx = fmaxf(sv[0][r], sv[1][r]);
#pragma unroll
                for (int off = 1; off < 16; off <<= 1) mx = fmaxf(mx, __shfl_xor(mx, off));
                pmax[r] = mx;
            }
            bool need = (pmax[0] > mrow[0] + 8.f) || (pmax[1] > mrow[1] + 8.f) ||
                        (pmax[2] > mrow[2] + 8.f) || (pmax[3] > mrow[3] + 8.f);
            if (__any(need)) {
#pragma unroll
                for (int r = 0; r < 4; ++r) {
                    float mnew = fmaxf(mrow[r], pmax[r]);
                    float alpha = fexp2(mrow[r] - mnew);
                    mrow[r] = mnew;
#pragma unroll
                    for (int d = 0; d < 8; ++d) o[d][r] *= alpha;
                    o9[r] *= alpha;
                }
            }
#pragma unroll
            for (int n = 0; n < 2; ++n)
#pragma unroll
                for (int r = 0; r < 4; ++r)
                    PsW[(lk * 4 + r) * 40 + n * 16 + lm] = f2bf(fexp2(sv[n][r] - mrow[r]));

            // O += P V  (P read back by same wave; l accumulated via ones-column)
            short8 pf = *(const short8*)&PsW[lm * 40 + lk * 8];
#pragma unroll
            for (int d = 0; d < 8; ++d) {
                short8 vf = *(const short8*)&VsS[lk * 1024 + (((d * 16 + lm) * 8) ^ (lk * 16))];
                o[d] = __builtin_amdgcn_mfma_f32_16x16x32_bf16(pf, vf, o[d], 0, 0, 0);
            }
            o9 = __builtin_amdgcn_mfma_f32_16x16x32_bf16(pf, bones, o9, 0, 0, 0);

            if (more) {
                __syncthreads();
#pragma unroll
                for (int i = 0; i < 3; ++i) {
                    int idx = i * 256 + t256; int r = idx / 24, c = (idx % 24) * 8;
                    *(short8*)&KsS[r * 200 + c] = kreg[i];
                }
#pragma unroll
                for (int i = 0; i < 2; ++i) {
                    int idx = i * 256 + t256; int dv = idx >> 2, kvb = idx & 3;
                    *(short8*)&VsS[kvb * 1024 + ((dv * 8) ^ (kvb * 16))] = vreg[i];
                }
                __syncthreads();
            }
        }

        // ---- combine splits through LDS ----
        __syncthreads();   // everyone done reading Ks/Vs (Ob aliases them)
        if (s == 1) {
#pragma unroll
            for (int d = 0; d < 8; ++d)
#pragma unroll
                for (int r = 0; r < 4; ++r)
                    Ob[(wp * 16 + lk * 4 + r) * 128 + d * 16 + lm] = o[d][r];
            if (lm == 0) {
#pragma unroll
                for (int r = 0; r < 4; ++r) {
                    ML[(wp * 16 + lk * 4 + r) * 2 + 0] = mrow[r];
                    ML[(wp * 16 + lk * 4 + r) * 2 + 1] = o9[r];   // l1 (lm==0 lane holds it)
                }
            }
        }
        __syncthreads();
        if (s == 0) {
            float e0[4], e1[4], inv[4];
#pragma unroll
            for (int r = 0; r < 4; ++r) {
                float m1 = ML[(wp * 16 + lk * 4 + r) * 2 + 0];
                float l1 = ML[(wp * 16 + lk * 4 + r) * 2 + 1];
                float l0 = __shfl(o9[r], lane & 48);
                float M = fmaxf(mrow[r], m1);
                e0[r] = fexp2(mrow[r] - M);
                e1[r] = fexp2(m1 - M);
                inv[r] = 1.f / (l0 * e0[r] + l1 * e1[r]);
            }
#pragma unroll
            for (int d = 0; d < 8; ++d)
#pragma unroll
                for (int r = 0; r < 4; ++r) {
                    float val = (o[d][r] * e0[r] +
                                 Ob[(wp * 16 + lk * 4 + r) * 128 + d * 16 + lm] * e1[r]) * inv[r];
                    Ao[((long)q0 + wp * 16 + lk * 4 + r) * 2048 + h * 128 + d * 16 + lm] = f2bf(val);
                }
        }
        __syncthreads();   // protect LDS before next half's staging
    }
}

// ---------------- host launch ----------------
extern "C" void kernel_launch(void* const* d_in, const int* in_sizes, int n_in,
                              void* d_out, int out_size, void* d_ws, size_t ws_size,
                              hipStream_t stream) {
    (void)in_sizes; (void)n_in; (void)out_size; (void)ws_size;
    const float* hidden  = (const float*)d_in[0];
    const float* q_a_w   = (const float*)d_in[1];
    const float* q_a_ln  = (const float*)d_in[2];
    const float* q_b_w   = (const float*)d_in[3];
    const float* kv_a_w  = (const float*)d_in[4];
    const float* kv_a_ln = (const float*)d_in[5];
    const float* kv_b_w  = (const float*)d_in[6];
    const float* o_w     = (const float*)d_in[7];
    const float* cosT    = (const float*)d_in[8];
    const float* sinT    = (const float*)d_in[9];
    const int*   pos     = (const int*)d_in[11];

    char* ws = (char*)d_ws;
    // persistent zone
    u16* o_w_bf   = (u16*)(ws + 0);          // 2048x2048
    u16* qb_w_bf  = (u16*)(ws + 8388608);    // 3072x1536
    u16* kvb_w_bf = (u16*)(ws + 17825792);   // 4096x512
    u16* qn_bf    = (u16*)(ws + 22020096);   // 2048x1536
    u16* kvn_bf   = (u16*)(ws + 28311552);   // 2048x512
    u16* Qb       = (u16*)(ws + 30408704);   // 16x2048x192
    u16* Kb       = (u16*)(ws + 42991616);   // 16x2048x192
    u16* Vt       = (u16*)(ws + 55574528);   // 16x128x2048
    u16* aout_bf  = (u16*)(ws + 63963136);   // 2048x2048
    // transient zone
    u16*   hid_bf    = (u16*)(ws + 72351744);   // 2048x2048 bf16
    u16*   qkva_w_bf = (u16*)(ws + 80740352);   // 2176x2048 bf16 (q_a_w ++ kv_a_w padded)
    float* qkva_f    = (float*)(ws + 89653248); // 2048x2176 f32 (ends 107,479,040)
    float* q_f       = (float*)(ws + 72351744); // 2048x3072 f32 (reuses hid+qkva_w)
    float* kv_f      = (float*)(ws + 97517568); // 2048x4096 f32 (ends 131,072,000)

    // converts
    conv_f32_bf16<<<(2048L*2048/4 + 255)/256, 256, 0, stream>>>(hidden, hid_bf, 2048L*2048/4);
    conv_f32_bf16<<<(1536L*2048/4 + 255)/256, 256, 0, stream>>>(q_a_w, qkva_w_bf, 1536L*2048/4);
    conv_pad   <<<(640L*2048/4 + 255)/256, 256, 0, stream>>>(kv_a_w, qkva_w_bf + 1536L*2048, 576, 640L*2048/4, 512);
    conv_f32_bf16<<<(3072L*1536/4 + 255)/256, 256, 0, stream>>>(q_b_w, qb_w_bf, 3072L*1536/4);
    conv_f32_bf16<<<(4096L*512/4 + 255)/256, 256, 0, stream>>>(kv_b_w, kvb_w_bf, 4096L*512/4);
    conv_f32_bf16<<<(2048L*2048/4 + 255)/256, 256, 0, stream>>>(o_w, o_w_bf, 2048L*2048/4);

    // fused down-projection: [2048,2048] x [2176,2048]^T -> [2048,2176]
    gemm_bt64<<<dim3(17, 32), 256, 0, stream>>>(hid_bf, qkva_w_bf, qkva_f, 2048, 2176, 2048);

    // norms + k_pe rope (all read the fused buffer)
    rmsnorm_bf16<<<2048, 256, 0, stream>>>(qkva_f, q_a_ln, qn_bf, 2176, 1536, 1536);
    rmsnorm_bf16<<<2048, 256, 0, stream>>>(qkva_f + 1536, kv_a_ln, kvn_bf, 2176, 512, 512);
    rope_k<<<(2048*32)/256, 256, 0, stream>>>(qkva_f, pos, cosT, sinT, Kb);

    // up-projections
    gemm_bt64<<<dim3(24, 32), 256, 0, stream>>>(qn_bf, qb_w_bf, q_f, 2048, 3072, 1536);
    gemm_bt<<<dim3(32, 16), 256, 0, stream>>>(kvn_bf, kvb_w_bf, kv_f, 2048, 4096, 512);

    // assemble Q/K/V
    build_q<<<(unsigned)((16L*2048*192 + 255)/256), 256, 0, stream>>>(q_f, pos, cosT, sinT, Qb);
    build_k<<<(unsigned)((16L*2048*128 + 255)/256), 256, 0, stream>>>(kv_f, Kb);
    vtrans<<<dim3(32, 2, 16), 256, 0, stream>>>(kv_f, Vt);

    // attention (256 blocks x 512 threads, in-block KV split)
    attn_fwd<<<256, 512, 0, stream>>>(Qb, Kb, Vt, aout_bf);

    // output projection -> d_out (f32)
    gemm_bt64<<<dim3(16, 32), 256, 0, stream>>>(aout_bf, o_w_bf, (float*)d_out, 2048, 2048, 2048);
}

// Round 4
// 255.774 us; speedup vs baseline: 1.8954x; 1.0973x over previous
//
#include <hip/hip_runtime.h>
#include <stdint.h>

typedef unsigned short u16;
typedef __attribute__((ext_vector_type(8))) short short8;
typedef __attribute__((ext_vector_type(4))) float f32x4;
typedef __attribute__((ext_vector_type(4))) unsigned short ushort4_t;
typedef __attribute__((ext_vector_type(4))) float float4_t;

#define DEV_INLINE __device__ __forceinline__

DEV_INLINE u16 f2bf(float f) {
    union { float f; unsigned u; } x; x.f = f;
    unsigned u = x.u;
    unsigned r = (u + 0x7FFFu + ((u >> 16) & 1u)) >> 16;
    return (u16)r;
}

DEV_INLINE float bf2f(u16 b) {
    union { unsigned u; float f; } x; x.u = ((unsigned)b) << 16;
    return x.f;
}

DEV_INLINE float fexp2(float x) {
    float r;
    asm("v_exp_f32 %0, %1" : "=v"(r) : "v"(x));
    return r;
}

// ---------------- fused convert (5 plain f32->bf16 segments) ----------------
__global__ void conv_multi(const float* __restrict__ s0, u16* __restrict__ d0, long e0,
                           const float* __restrict__ s1, u16* __restrict__ d1, long e1,
                           const float* __restrict__ s2, u16* __restrict__ d2, long e2,
                           const float* __restrict__ s3, u16* __restrict__ d3, long e3,
                           const float* __restrict__ s4, u16* __restrict__ d4, long e4) {
    long i = (long)blockIdx.x * 256 + threadIdx.x;
    const float* s; u16* d; long base;
    if      (i < e0) { s = s0; d = d0; base = 0; }
    else if (i < e1) { s = s1; d = d1; base = e0; }
    else if (i < e2) { s = s2; d = d2; base = e1; }
    else if (i < e3) { s = s3; d = d3; base = e2; }
    else if (i < e4) { s = s4; d = d4; base = e3; }
    else return;
    long j = i - base;
    float4_t v = ((const float4_t*)s)[j];
    ushort4_t o;
    o.x = f2bf(v.x); o.y = f2bf(v.y); o.z = f2bf(v.z); o.w = f2bf(v.w);
    ((ushort4_t*)d)[j] = o;
}

__global__ void conv_pad(const float* __restrict__ in, u16* __restrict__ out,
                         int rows_valid, long n4, int cols4) {
    long i = (long)blockIdx.x * blockDim.x + threadIdx.x;
    if (i >= n4) return;
    long row = i / cols4;
    ushort4_t o; o.x = 0; o.y = 0; o.z = 0; o.w = 0;
    if (row < rows_valid) {
        float4_t v = ((const float4_t*)in)[i];
        o.x = f2bf(v.x); o.y = f2bf(v.y); o.z = f2bf(v.z); o.w = f2bf(v.w);
    }
    ((ushort4_t*)out)[i] = o;
}

// ---------------- GEMM 64x128 double-buffered: C[M,N] = A[M,K]*B[N,K]^T ----------------
#define BK 32

DEV_INLINE void gload16(const u16* g, u16* l) {
    __builtin_amdgcn_global_load_lds((const __attribute__((address_space(1))) unsigned int*)g,
                                     (__attribute__((address_space(3))) unsigned int*)l,
                                     16, 0, 0);
}

template <typename OT>
__global__ __launch_bounds__(256) void gemm64_db(const u16* __restrict__ A, const u16* __restrict__ B,
                                                 OT* __restrict__ C, int M, int N, int K) {
    __shared__ u16 As[2][64 * BK];
    __shared__ u16 Bs[2][128 * BK];
    const int tid = threadIdx.x;
    const int wid = tid >> 6, lane = tid & 63;
    const int lm = lane & 15, lk = lane >> 4;
    const long bm = (long)blockIdx.y * 64, bn = (long)blockIdx.x * 128;

    f32x4 acc[4][2] = {};

    const int rowS = lane >> 2;
    const int colS = ((lane & 3) ^ ((lane >> 3) & 3)) * 8;  // pre-swizzled source col
    const int cs = (lm >> 1) & 3;                           // frag-read XOR
    const u16* Ag = A + (bm + wid * 16 + rowS) * (long)K + colS;
    const u16* Bg = B + (bn + wid * 32 + rowS) * (long)K + colS;
    const int aoff = wid * 16 * BK;
    const int boff = wid * 32 * BK;

    // prologue: stage buffer 0
    gload16(Ag, &As[0][aoff]);
    gload16(Bg, &Bs[0][boff]);
    gload16(Bg + 16 * (long)K, &Bs[0][boff + 16 * BK]);
    __syncthreads();

    int cur = 0;
    for (int k0 = 0; k0 < K; k0 += BK) {
        // issue next tile's stage first (overlaps with compute below)
        if (k0 + BK < K) {
            gload16(Ag + k0 + BK, &As[cur ^ 1][aoff]);
            gload16(Bg + k0 + BK, &Bs[cur ^ 1][boff]);
            gload16(Bg + 16 * (long)K + k0 + BK, &Bs[cur ^ 1][boff + 16 * BK]);
        }
        short8 af[4], bfr[2];
#pragma unroll
        for (int m = 0; m < 4; ++m)
            af[m] = *(const short8*)&As[cur][(m * 16 + lm) * BK + (lk ^ cs) * 8];
#pragma unroll
        for (int n = 0; n < 2; ++n)
            bfr[n] = *(const short8*)&Bs[cur][(wid * 32 + n * 16 + lm) * BK + (lk ^ cs) * 8];
#pragma unroll
        for (int m = 0; m < 4; ++m)
#pragma unroll
            for (int n = 0; n < 2; ++n)
                acc[m][n] = __builtin_amdgcn_mfma_f32_16x16x32_bf16(af[m], bfr[n], acc[m][n], 0, 0, 0);
        __syncthreads();   // drains vmcnt (stage done) + all waves done reading buf
        cur ^= 1;
    }

#pragma unroll
    for (int m = 0; m < 4; ++m)
#pragma unroll
        for (int n = 0; n < 2; ++n)
#pragma unroll
            for (int r = 0; r < 4; ++r) {
                long idx = (bm + m * 16 + lk * 4 + r) * (long)N + bn + wid * 32 + n * 16 + lm;
                if constexpr (sizeof(OT) == 4) C[idx] = acc[m][n][r];
                else                           C[idx] = f2bf(acc[m][n][r]);
            }
}

// ---------------- RMSNorm (f32 in, bf16 out) ----------------
__global__ __launch_bounds__(256) void rmsnorm_bf16(const float* __restrict__ in, const float* __restrict__ w,
                                                    u16* __restrict__ out, int ldin, int ldout, int ncols) {
    const int row = blockIdx.x, tid = threadIdx.x;
    const float* x = in + (long)row * ldin;
    float ss = 0.f;
    for (int c = tid; c < ncols; c += 256) { float v = x[c]; ss = fmaf(v, v, ss); }
#pragma unroll
    for (int off = 32; off > 0; off >>= 1) ss += __shfl_down(ss, off);
    __shared__ float part[4];
    if ((tid & 63) == 0) part[tid >> 6] = ss;
    __syncthreads();
    float tot = part[0] + part[1] + part[2] + part[3];
    float rs = rsqrtf(tot / (float)ncols + 1e-6f);
    for (int c = tid; c < ncols; c += 256) out[(long)row * ldout + c] = f2bf(x[c] * rs * w[c]);
}

// ---------------- k_pe RoPE -> K[:, :, 128:192] for all heads ----------------
__global__ void rope_k(const float* __restrict__ ckv, const int* __restrict__ pos,
                       const float* __restrict__ cosT, const float* __restrict__ sinT,
                       u16* __restrict__ Kb) {
    int idx = blockIdx.x * 256 + threadIdx.x;
    if (idx >= 2048 * 32) return;
    int s = idx >> 5, j = idx & 31;
    long p = pos[s];
    const float* row = ckv + (long)s * 2176 + 2048;   // k_pe cols in fused buffer
    float x0 = row[2 * j], x1 = row[2 * j + 1];
    float c0 = cosT[p * 64 + j],      s0 = sinT[p * 64 + j];
    float c1 = cosT[p * 64 + 32 + j], s1 = sinT[p * 64 + 32 + j];
    u16 o0 = f2bf(x0 * c0 - x1 * s0);
    u16 o1 = f2bf(x1 * c1 + x0 * s1);
#pragma unroll
    for (int h = 0; h < 16; ++h) {
        u16* kr = Kb + ((long)h * 2048 + s) * 192 + 128;
        kr[j] = o0; kr[32 + j] = o1;
    }
}

// ---------------- assemble Q (bf16 in, RoPE on last 64 dims) ----------------
__global__ void build_q(const u16* __restrict__ q, const int* __restrict__ pos,
                        const float* __restrict__ cosT, const float* __restrict__ sinT,
                        u16* __restrict__ Qb) {
    long idx = (long)blockIdx.x * 256 + threadIdx.x;
    if (idx >= 16L * 2048 * 192) return;
    int d = (int)(idx % 192);
    int s = (int)((idx / 192) % 2048);
    int h = (int)(idx / (192L * 2048));
    const u16* qrow = q + (long)s * 3072 + h * 192;
    u16 outv;
    if (d < 128) {
        outv = qrow[d];
    } else {
        long p = pos[s];
        int dd = d - 128;
        float cv = cosT[p * 64 + dd], sv = sinT[p * 64 + dd];
        float val;
        if (dd < 32) val = bf2f(qrow[128 + 2 * dd]) * cv - bf2f(qrow[128 + 2 * dd + 1]) * sv;
        else { int jj = dd - 32; val = bf2f(qrow[128 + 2 * jj + 1]) * cv + bf2f(qrow[128 + 2 * jj]) * sv; }
        outv = f2bf(val);
    }
    Qb[((long)h * 2048 + s) * 192 + d] = outv;
}

// ---------------- K-nope copy + V transpose (single pass over kv, bf16 in) ----------------
__global__ __launch_bounds__(256) void build_kv2(const u16* __restrict__ kv, u16* __restrict__ Kb,
                                                 u16* __restrict__ Vt) {
    __shared__ u16 Ls[128][72];   // V^T staging, col-swizzled
    const int h = blockIdx.y, s0 = blockIdx.x * 64;
    const int tid = threadIdx.x;
#pragma unroll
    for (int i = 0; i < 8; ++i) {
        int u = i * 256 + tid;
        int r = u >> 5, c8 = (u & 31) * 8;
        short8 x = *(const short8*)(kv + (long)(s0 + r) * 4096 + h * 256 + c8);
        if (c8 < 128) {
            *(short8*)(Kb + ((long)h * 2048 + s0 + r) * 192 + c8) = x;
        } else {
#pragma unroll
            for (int j = 0; j < 8; ++j) {
                int d = c8 - 128 + j;
                Ls[d][r ^ (((d >> 3) & 7) << 3)] = (u16)x[j];
            }
        }
    }
    __syncthreads();
#pragma unroll
    for (int i = 0; i < 8; ++i) {
        int u = i * 256 + tid;
        int d = u >> 4, s4 = (u & 15) * 4;
        int swz = ((d >> 3) & 7) << 3;
        ushort4_t v;
        v.x = Ls[d][(s4 + 0) ^ swz]; v.y = Ls[d][(s4 + 1) ^ swz];
        v.z = Ls[d][(s4 + 2) ^ swz]; v.w = Ls[d][(s4 + 3) ^ swz];
        *(ushort4_t*)(Vt + ((long)h * 128 + d) * 2048 + s0 + s4) = v;
    }
}

// ---------------- causal flash attention: 8-wave in-block KV split ----------------
__global__ __launch_bounds__(512, 2) void attn_fwd(const u16* __restrict__ Qb, const u16* __restrict__ Kb,
                                                   const u16* __restrict__ Vt, u16* __restrict__ Ao) {
    // smem layout:
    //  [0,25600):     Ks[2][32][200] u16
    //  [25600,41984): Vs[2][4096] u16 (XOR-swizzled V^T)
    //  Ob alias [0,32768): float[4][16][128]
    //  [41984,52224): Ps[8][16][40] u16 (XOR col swizzle)
    //  [52224,52736): ML float[4][16][2]
    __shared__ __align__(16) char smem[52736];

    const int b = blockIdx.x;
    const int h = (b & 7) * 2 + ((b >> 3) & 1);
    const int pi = b >> 4;
    const int tid = threadIdx.x;
    const int wid = tid >> 6, lane = tid & 63;
    const int lm = lane & 15, lk = lane >> 4;
    const int s = wid >> 2;
    const int wp = wid & 3;
    const int t256 = tid & 255;

    u16* KsS = (u16*)(smem) + s * 6400;
    u16* VsS = (u16*)(smem + 25600) + s * 4096;
    u16* PsW = (u16*)(smem + 41984) + wid * 640;
    float* ML = (float*)(smem + 52224);
    float* Ob = (float*)smem;

    const u16* Kh = Kb + (long)h * 2048 * 192;
    const u16* Vh = Vt + (long)h * 128 * 2048;

    short8 bones = {};
    if (lm == 0) {
#pragma unroll
        for (int j = 0; j < 8; ++j) bones[j] = (short)0x3F80;   // bf16 1.0
    }
    const float C2 = 0.104117548f;   // 192^-0.5 * log2(e)

    for (int half = 0; half < 2; ++half) {
        const int qi = half ? (31 - pi) : pi;
        const int q0 = qi * 64;
        const int nt = 2 * qi + 2;
        const int niter = qi + 1;

        short8 qf[6];
        const u16* qbase = Qb + ((long)h * 2048 + q0 + wp * 16 + lm) * 192;
#pragma unroll
        for (int kf = 0; kf < 6; ++kf) qf[kf] = *(const short8*)(qbase + kf * 32 + lk * 8);

        f32x4 o[8] = {};
        f32x4 o9 = {};
        float mrow[4] = {-1e30f, -1e30f, -1e30f, -1e30f};

        short8 kreg[3], vreg[2];
        {
            const long k0 = s * 32;
#pragma unroll
            for (int i = 0; i < 3; ++i) {
                int idx = i * 256 + t256; int r = idx / 24, c = (idx % 24) * 8;
                kreg[i] = *(const short8*)(Kh + (k0 + r) * 192 + c);
            }
#pragma unroll
            for (int i = 0; i < 2; ++i) {
                int idx = i * 256 + t256; int dv = idx >> 2, kvb = idx & 3;
                vreg[i] = *(const short8*)(Vh + (long)dv * 2048 + k0 + kvb * 8);
            }
#pragma unroll
            for (int i = 0; i < 3; ++i) {
                int idx = i * 256 + t256; int r = idx / 24, c = (idx % 24) * 8;
                *(short8*)&KsS[r * 200 + c] = kreg[i];
            }
#pragma unroll
            for (int i = 0; i < 2; ++i) {
                int idx = i * 256 + t256; int dv = idx >> 2, kvb = idx & 3;
                *(short8*)&VsS[kvb * 1024 + ((dv * 8) ^ (kvb * 16))] = vreg[i];
            }
        }
        __syncthreads();

        for (int it = 0; it < niter; ++it) {
            const int ts = 2 * it + s;
            const int k0 = ts * 32;
            const bool more = (it + 1 < niter);

            if (more) {
                const long k0n = (long)(2 * (it + 1) + s) * 32;
#pragma unroll
                for (int i = 0; i < 3; ++i) {
                    int idx = i * 256 + t256; int r = idx / 24, c = (idx % 24) * 8;
                    kreg[i] = *(const short8*)(Kh + (k0n + r) * 192 + c);
                }
#pragma unroll
                for (int i = 0; i < 2; ++i) {
                    int idx = i * 256 + t256; int dv = idx >> 2, kvb = idx & 3;
                    vreg[i] = *(const short8*)(Vh + (long)dv * 2048 + k0n + kvb * 8);
                }
            }

            // S = Q K^T
            f32x4 sfr[2] = {};
            __builtin_amdgcn_s_setprio(1);
#pragma unroll
            for (int n = 0; n < 2; ++n)
#pragma unroll
                for (int kf = 0; kf < 6; ++kf) {
                    short8 kb = *(const short8*)&KsS[(n * 16 + lm) * 200 + kf * 32 + lk * 8];
                    sfr[n] = __builtin_amdgcn_mfma_f32_16x16x32_bf16(qf[kf], kb, sfr[n], 0, 0, 0);
                }
            __builtin_amdgcn_s_setprio(0);

            float sv[2][4];
            const bool bt = (ts >= nt - 2);
#pragma unroll
            for (int n = 0; n < 2; ++n)
#pragma unroll
                for (int r = 0; r < 4; ++r) {
                    float val = sfr[n][r] * C2;
                    if (bt && (k0 + n * 16 + lm > q0 + wp * 16 + lk * 4 + r)) val = -1e30f;
                    sv[n][r] = val;
                }

            // online softmax (base-2), deferred-max rescale
            float pmax[4];
#pragma unroll
            for (int r = 0; r < 4; ++r) {
                float mx = fmaxf(sv[0][r], sv[1][r]);
#pragma unroll
                for (int off = 1; off < 16; off <<= 1) mx = fmaxf(mx, __shfl_xor(mx, off));
                pmax[r] = mx;
            }
            bool need = (pmax[0] > mrow[0] + 8.f) || (pmax[1] > mrow[1] + 8.f) ||
                        (pmax[2] > mrow[2] + 8.f) || (pmax[3] > mrow[3] + 8.f);
            if (__any(need)) {
#pragma unroll
                for (int r = 0; r < 4; ++r) {
                    float mnew = fmaxf(mrow[r], pmax[r]);
                    float alpha = fexp2(mrow[r] - mnew);
                    mrow[r] = mnew;
#pragma unroll
                    for (int d = 0; d < 8; ++d) o[d][r] *= alpha;
                    o9[r] *= alpha;
                }
            }
#pragma unroll
            for (int n = 0; n < 2; ++n)
#pragma unroll
                for (int r = 0; r < 4; ++r)
                    PsW[(lk * 4 + r) * 40 + ((n * 16 + lm) ^ (lk << 3))] = f2bf(fexp2(sv[n][r] - mrow[r]));

            // O += P V   (ones-column accumulates row-sum l into o9)
            short8 pf = *(const short8*)&PsW[lm * 40 + ((lk ^ ((lm >> 2) & 3)) << 3)];
            __builtin_amdgcn_s_setprio(1);
#pragma unroll
            for (int d = 0; d < 8; ++d) {
                short8 vf = *(const short8*)&VsS[lk * 1024 + (((d * 16 + lm) * 8) ^ (lk * 16))];
                o[d] = __builtin_amdgcn_mfma_f32_16x16x32_bf16(pf, vf, o[d], 0, 0, 0);
            }
            o9 = __builtin_amdgcn_mfma_f32_16x16x32_bf16(pf, bones, o9, 0, 0, 0);
            __builtin_amdgcn_s_setprio(0);

            if (more) {
                __syncthreads();
#pragma unroll
                for (int i = 0; i < 3; ++i) {
                    int idx = i * 256 + t256; int r = idx / 24, c = (idx % 24) * 8;
                    *(short8*)&KsS[r * 200 + c] = kreg[i];
                }
#pragma unroll
                for (int i = 0; i < 2; ++i) {
                    int idx = i * 256 + t256; int dv = idx >> 2, kvb = idx & 3;
                    *(short8*)&VsS[kvb * 1024 + ((dv * 8) ^ (kvb * 16))] = vreg[i];
                }
                __syncthreads();
            }
        }

        // ---- combine splits through LDS ----
        __syncthreads();
        if (s == 1) {
#pragma unroll
            for (int d = 0; d < 8; ++d)
#pragma unroll
                for (int r = 0; r < 4; ++r)
                    Ob[(wp * 16 + lk * 4 + r) * 128 + d * 16 + lm] = o[d][r];
            if (lm == 0) {
#pragma unroll
                for (int r = 0; r < 4; ++r) {
                    ML[(wp * 16 + lk * 4 + r) * 2 + 0] = mrow[r];
                    ML[(wp * 16 + lk * 4 + r) * 2 + 1] = o9[r];
                }
            }
        }
        __syncthreads();
        if (s == 0) {
            float e0[4], e1[4], inv[4];
#pragma unroll
            for (int r = 0; r < 4; ++r) {
                float m1 = ML[(wp * 16 + lk * 4 + r) * 2 + 0];
                float l1 = ML[(wp * 16 + lk * 4 + r) * 2 + 1];
                float l0 = __shfl(o9[r], lane & 48);
                float M = fmaxf(mrow[r], m1);
                e0[r] = fexp2(mrow[r] - M);
                e1[r] = fexp2(m1 - M);
                inv[r] = 1.f / (l0 * e0[r] + l1 * e1[r]);
            }
#pragma unroll
            for (int d = 0; d < 8; ++d)
#pragma unroll
                for (int r = 0; r < 4; ++r) {
                    float val = (o[d][r] * e0[r] +
                                 Ob[(wp * 16 + lk * 4 + r) * 128 + d * 16 + lm] * e1[r]) * inv[r];
                    Ao[((long)q0 + wp * 16 + lk * 4 + r) * 2048 + h * 128 + d * 16 + lm] = f2bf(val);
                }
        }
        __syncthreads();
    }
}

// ---------------- host launch ----------------
extern "C" void kernel_launch(void* const* d_in, const int* in_sizes, int n_in,
                              void* d_out, int out_size, void* d_ws, size_t ws_size,
                              hipStream_t stream) {
    (void)in_sizes; (void)n_in; (void)out_size; (void)ws_size;
    const float* hidden  = (const float*)d_in[0];
    const float* q_a_w   = (const float*)d_in[1];
    const float* q_a_ln  = (const float*)d_in[2];
    const float* q_b_w   = (const float*)d_in[3];
    const float* kv_a_w  = (const float*)d_in[4];
    const float* kv_a_ln = (const float*)d_in[5];
    const float* kv_b_w  = (const float*)d_in[6];
    const float* o_w     = (const float*)d_in[7];
    const float* cosT    = (const float*)d_in[8];
    const float* sinT    = (const float*)d_in[9];
    const int*   pos     = (const int*)d_in[11];

    char* ws = (char*)d_ws;
    // persistent zone
    u16* o_w_bf   = (u16*)(ws + 0);          // 2048x2048
    u16* qb_w_bf  = (u16*)(ws + 8388608);    // 3072x1536
    u16* kvb_w_bf = (u16*)(ws + 17825792);   // 4096x512
    u16* qn_bf    = (u16*)(ws + 22020096);   // 2048x1536
    u16* kvn_bf   = (u16*)(ws + 28311552);   // 2048x512
    u16* Qb       = (u16*)(ws + 30408704);   // 16x2048x192
    u16* Kb       = (u16*)(ws + 42991616);   // 16x2048x192
    u16* Vt       = (u16*)(ws + 55574528);   // 16x128x2048
    u16* aout_bf  = (u16*)(ws + 63963136);   // 2048x2048, ends 72351744
    // transient zone
    u16*   hid_bf    = (u16*)(ws + 72351744);   // 2048x2048 bf16
    u16*   qkva_w_bf = (u16*)(ws + 80740352);   // 2176x2048 bf16
    float* qkva_f    = (float*)(ws + 89653248); // 2048x2176 f32, ends 107479040
    u16*   q_f_bf    = (u16*)(ws + 72351744);   // 2048x3072 bf16 (reuses hid+part of qkva_w)
    u16*   kv_f_bf   = (u16*)(ws + 89653248);   // 2048x4096 bf16 (reuses qkva_f)

    // converts (one fused kernel + the padded one)
    conv_multi<<<17920, 256, 0, stream>>>(
        hidden, hid_bf,               1048576L,
        q_a_w,  qkva_w_bf,            1835008L,
        q_b_w,  qb_w_bf,              3014656L,
        kv_b_w, kvb_w_bf,             3538944L,
        o_w,    o_w_bf,               4587520L);
    conv_pad<<<(640L*2048/4 + 255)/256, 256, 0, stream>>>(kv_a_w, qkva_w_bf + 1536L*2048, 576, 640L*2048/4, 512);

    // fused down-projection: [2048,2048] x [2176,2048]^T -> [2048,2176] f32
    gemm64_db<float><<<dim3(17, 32), 256, 0, stream>>>(hid_bf, qkva_w_bf, qkva_f, 2048, 2176, 2048);

    // norms + k_pe rope
    rmsnorm_bf16<<<2048, 256, 0, stream>>>(qkva_f, q_a_ln, qn_bf, 2176, 1536, 1536);
    rmsnorm_bf16<<<2048, 256, 0, stream>>>(qkva_f + 1536, kv_a_ln, kvn_bf, 2176, 512, 512);
    rope_k<<<(2048*32)/256, 256, 0, stream>>>(qkva_f, pos, cosT, sinT, Kb);

    // up-projections (bf16 outputs)
    gemm64_db<u16><<<dim3(24, 32), 256, 0, stream>>>(qn_bf, qb_w_bf, q_f_bf, 2048, 3072, 1536);
    gemm64_db<u16><<<dim3(32, 32), 256, 0, stream>>>(kvn_bf, kvb_w_bf, kv_f_bf, 2048, 4096, 512);

    // assemble Q / K-nope+V^T
    build_q<<<(unsigned)((16L*2048*192 + 255)/256), 256, 0, stream>>>(q_f_bf, pos, cosT, sinT, Qb);
    build_kv2<<<dim3(32, 16), 256, 0, stream>>>(kv_f_bf, Kb, Vt);

    // attention
    attn_fwd<<<256, 512, 0, stream>>>(Qb, Kb, Vt, aout_bf);

    // output projection -> d_out (f32)
    gemm64_db<float><<<dim3(16, 32), 256, 0, stream>>>(aout_bf, o_w_bf, (float*)d_out, 2048, 2048, 2048);
}